// Round 6
// baseline (2518.135 us; speedup 1.0000x reference)
//
#include <hip/hip_runtime.h>

#define N_NODES 500000
#define N_EDGES 16000000

// bucketing: 1024 dst-nodes per bucket
#define BKT_BITS 10
#define BKT_SIZE (1 << BKT_BITS)
#define NBUCKET ((N_NODES + BKT_SIZE - 1) / BKT_SIZE)       // 489
#define BIN_EPT 128
#define BIN_CHUNK (256 * BIN_EPT)                            // 32768 edges
#define BIN_NBLK ((N_EDGES + BIN_CHUNK - 1) / BIN_CHUNK)     // 489
#define BIN_VQ (BIN_EPT / 4)                                 // 32 int4/thread
#define NV4 (N_EDGES / 4)                                    // 4M int4

// ---------------------------------------------------------------------------
// Bucket histogram (489 bins): per-block LDS aggregation, int4 edge reads.
// ---------------------------------------------------------------------------
__global__ __launch_bounds__(256) void bucket_hist_kernel(
    const int* __restrict__ dst, int* __restrict__ bhist)
{
    __shared__ int lh[NBUCKET];
    const int4* dst4 = (const int4*)dst;
    int t = threadIdx.x;
    long v0 = (long)blockIdx.x * (BIN_CHUNK / 4);
    for (int b = t; b < NBUCKET; b += 256) lh[b] = 0;
    __syncthreads();
#pragma unroll
    for (int q = 0; q < BIN_VQ; ++q) {
        long v = v0 + q * 256 + t;
        if (v < NV4) {
            int4 d = dst4[v];
            atomicAdd(&lh[d.x >> BKT_BITS], 1);
            atomicAdd(&lh[d.y >> BKT_BITS], 1);
            atomicAdd(&lh[d.z >> BKT_BITS], 1);
            atomicAdd(&lh[d.w >> BKT_BITS], 1);
        }
    }
    __syncthreads();
    for (int b = t; b < NBUCKET; b += 256) {
        int c = lh[b];
        if (c) atomicAdd(&bhist[b], c);
    }
}

// single-block exclusive scan of 489 bucket totals -> bbase[0..NBUCKET], bcur
__global__ __launch_bounds__(512) void bucket_scan_kernel(
    const int* __restrict__ bhist, int* __restrict__ bbase, int* __restrict__ bcur)
{
    __shared__ int sdata[512];
    int t = threadIdx.x;
    int v = (t < NBUCKET) ? bhist[t] : 0;
    sdata[t] = v;
    __syncthreads();
    for (int o = 1; o < 512; o <<= 1) {
        int tmp = (t >= o) ? sdata[t - o] : 0;
        __syncthreads();
        sdata[t] += tmp;
        __syncthreads();
    }
    if (t < NBUCKET) {
        int excl = sdata[t] - v;
        bbase[t] = excl;
        bcur[t] = excl;
        if (t == NBUCKET - 1) bbase[NBUCKET] = sdata[t];
    }
}

// ---------------------------------------------------------------------------
// Bin edges into buckets. LDS histogram -> one global atomicAdd per
// (block,bucket) -> long clustered runs. pairs[pos] = (src<<10)|(dst&1023)
// ---------------------------------------------------------------------------
__global__ __launch_bounds__(256) void bin_kernel(
    const int* __restrict__ src, const int* __restrict__ dst,
    int* __restrict__ bcur, unsigned int* __restrict__ pairs)
{
    __shared__ int lh[NBUCKET];
    __shared__ int lbase[NBUCKET];
    const int4* dst4 = (const int4*)dst;
    const int4* src4 = (const int4*)src;
    int t = threadIdx.x;
    long v0 = (long)blockIdx.x * (BIN_CHUNK / 4);

    for (int b = t; b < NBUCKET; b += 256) lh[b] = 0;
    __syncthreads();

#pragma unroll
    for (int q = 0; q < BIN_VQ; ++q) {
        long v = v0 + q * 256 + t;
        if (v < NV4) {
            int4 d = dst4[v];
            atomicAdd(&lh[d.x >> BKT_BITS], 1);
            atomicAdd(&lh[d.y >> BKT_BITS], 1);
            atomicAdd(&lh[d.z >> BKT_BITS], 1);
            atomicAdd(&lh[d.w >> BKT_BITS], 1);
        }
    }
    __syncthreads();

    for (int b = t; b < NBUCKET; b += 256) {
        int c = lh[b];
        lbase[b] = c ? atomicAdd(&bcur[b], c) : 0;
        lh[b] = 0;   // reuse as running counter
    }
    __syncthreads();

#pragma unroll
    for (int q = 0; q < BIN_VQ; ++q) {
        long v = v0 + q * 256 + t;
        if (v < NV4) {
            int4 d = dst4[v];
            int4 s = src4[v];
            {
                int b = d.x >> BKT_BITS;
                int r = atomicAdd(&lh[b], 1);
                pairs[lbase[b] + r] = ((unsigned int)s.x << BKT_BITS) | (unsigned int)(d.x & (BKT_SIZE - 1));
            }
            {
                int b = d.y >> BKT_BITS;
                int r = atomicAdd(&lh[b], 1);
                pairs[lbase[b] + r] = ((unsigned int)s.y << BKT_BITS) | (unsigned int)(d.y & (BKT_SIZE - 1));
            }
            {
                int b = d.z >> BKT_BITS;
                int r = atomicAdd(&lh[b], 1);
                pairs[lbase[b] + r] = ((unsigned int)s.z << BKT_BITS) | (unsigned int)(d.z & (BKT_SIZE - 1));
            }
            {
                int b = d.w >> BKT_BITS;
                int r = atomicAdd(&lh[b], 1);
                pairs[lbase[b] + r] = ((unsigned int)s.w << BKT_BITS) | (unsigned int)(d.w & (BKT_SIZE - 1));
            }
        }
    }
}

// ---------------------------------------------------------------------------
// Layer 1 (din=1 -> dout=4, stride 4): one block per bucket.
// Accumulate x[src] into LDS acc[low] (x is 2MB -> L2-hot), then fused
// transform writes h1 coalesced.
// ---------------------------------------------------------------------------
__global__ __launch_bounds__(512) void layer1_kernel(
    const int* __restrict__ bbase, const unsigned int* __restrict__ pairs,
    const float* __restrict__ x,
    const float* __restrict__ Wrel, const float* __restrict__ brel,
    const float* __restrict__ Wroot,
    float* __restrict__ h1)
{
    __shared__ float acc[BKT_SIZE];
    __shared__ float w[12];
    int b = blockIdx.x, t = threadIdx.x;
    int base = b << BKT_BITS;
    int start = bbase[b], end = bbase[b + 1];

    for (int i = t; i < BKT_SIZE; i += 512) acc[i] = 0.0f;
    if (t < 4) { w[t] = Wrel[t]; w[4 + t] = brel[t]; w[8 + t] = Wroot[t]; }
    __syncthreads();

    int e = start + t;
    while (e + 512 < end) {
        unsigned int p0 = pairs[e], p1 = pairs[e + 512];
        float v0 = x[p0 >> BKT_BITS];
        float v1 = x[p1 >> BKT_BITS];
        atomicAdd(&acc[p0 & (BKT_SIZE - 1)], v0);
        atomicAdd(&acc[p1 & (BKT_SIZE - 1)], v1);
        e += 1024;
    }
    while (e < end) {
        unsigned int p = pairs[e];
        atomicAdd(&acc[p & (BKT_SIZE - 1)], x[p >> BKT_BITS]);
        e += 512;
    }
    __syncthreads();

    for (int i = t; i < BKT_SIZE; i += 512) {
        int node = base + i;
        if (node >= N_NODES) continue;
        float a = acc[i], xv = x[node];
        float4 r;
        r.x = fmaxf(a * w[0] + w[4] + xv * w[8],  0.0f);
        r.y = fmaxf(a * w[1] + w[5] + xv * w[9],  0.0f);
        r.z = fmaxf(a * w[2] + w[6] + xv * w[10], 0.0f);
        r.w = fmaxf(a * w[3] + w[7] + xv * w[11], 0.0f);
        *(float4*)(h1 + (size_t)node * 4) = r;
    }
}

// ---------------------------------------------------------------------------
// Layer 2 (din=4 stride 4 -> dout=7 stride 8): 1 lane per edge, float4 row
// load, 4 LDS atomics (acc stride 5: odd -> banks spread). Fused transform.
// ---------------------------------------------------------------------------
__global__ __launch_bounds__(512) void layer2_kernel(
    const int* __restrict__ bbase, const unsigned int* __restrict__ pairs,
    const float* __restrict__ h1,
    const float* __restrict__ Wrel, const float* __restrict__ brel,
    const float* __restrict__ Wroot,
    float* __restrict__ h2)
{
    __shared__ float acc[BKT_SIZE * 5];
    __shared__ float sWr[28], sWo[28], sb[7];
    int b = blockIdx.x, t = threadIdx.x;
    int base = b << BKT_BITS;
    int start = bbase[b], end = bbase[b + 1];

    for (int i = t; i < BKT_SIZE * 5; i += 512) acc[i] = 0.0f;
    if (t < 28) { sWr[t] = Wrel[t]; sWo[t] = Wroot[t]; }
    if (t < 7) sb[t] = brel[t];
    __syncthreads();

    int e = start + t;
    while (e + 512 < end) {
        unsigned int p0 = pairs[e], p1 = pairs[e + 512];
        float4 v0 = *(const float4*)(h1 + (size_t)(p0 >> BKT_BITS) * 4);
        float4 v1 = *(const float4*)(h1 + (size_t)(p1 >> BKT_BITS) * 4);
        int l0 = (int)(p0 & (BKT_SIZE - 1)) * 5;
        int l1 = (int)(p1 & (BKT_SIZE - 1)) * 5;
        atomicAdd(&acc[l0 + 0], v0.x); atomicAdd(&acc[l0 + 1], v0.y);
        atomicAdd(&acc[l0 + 2], v0.z); atomicAdd(&acc[l0 + 3], v0.w);
        atomicAdd(&acc[l1 + 0], v1.x); atomicAdd(&acc[l1 + 1], v1.y);
        atomicAdd(&acc[l1 + 2], v1.z); atomicAdd(&acc[l1 + 3], v1.w);
        e += 1024;
    }
    while (e < end) {
        unsigned int p = pairs[e];
        float4 v = *(const float4*)(h1 + (size_t)(p >> BKT_BITS) * 4);
        int l = (int)(p & (BKT_SIZE - 1)) * 5;
        atomicAdd(&acc[l + 0], v.x); atomicAdd(&acc[l + 1], v.y);
        atomicAdd(&acc[l + 2], v.z); atomicAdd(&acc[l + 3], v.w);
        e += 512;
    }
    __syncthreads();

    for (int i = t; i < BKT_SIZE; i += 512) {
        int node = base + i;
        if (node >= N_NODES) continue;
        float a0 = acc[i * 5], a1 = acc[i * 5 + 1], a2 = acc[i * 5 + 2], a3 = acc[i * 5 + 3];
        float4 xv = *(const float4*)(h1 + (size_t)node * 4);
        float o_[8];
#pragma unroll
        for (int o = 0; o < 7; ++o) {
            float v = sb[o]
                    + a0 * sWr[0 * 7 + o] + a1 * sWr[1 * 7 + o]
                    + a2 * sWr[2 * 7 + o] + a3 * sWr[3 * 7 + o]
                    + xv.x * sWo[0 * 7 + o] + xv.y * sWo[1 * 7 + o]
                    + xv.z * sWo[2 * 7 + o] + xv.w * sWo[3 * 7 + o];
            o_[o] = fmaxf(v, 0.0f);
        }
        o_[7] = 0.0f;
        float4* op = (float4*)(h2 + (size_t)node * 8);
        op[0] = make_float4(o_[0], o_[1], o_[2], o_[3]);
        op[1] = make_float4(o_[4], o_[5], o_[6], o_[7]);
    }
}

// ---------------------------------------------------------------------------
// Layer 3 (din=7 stride 8 -> dout=10 stride 16): 2 lanes per edge (float4
// each), acc stride 9. Fused transform writes h3 (pads zeroed).
// ---------------------------------------------------------------------------
__global__ __launch_bounds__(512) void layer3_kernel(
    const int* __restrict__ bbase, const unsigned int* __restrict__ pairs,
    const float* __restrict__ h2,
    const float* __restrict__ Wrel, const float* __restrict__ brel,
    const float* __restrict__ Wroot,
    float* __restrict__ h3)
{
    __shared__ float acc[BKT_SIZE * 9];
    __shared__ float sWr[70], sWo[70], sb[10];
    int b = blockIdx.x, t = threadIdx.x;
    int base = b << BKT_BITS;
    int start = bbase[b], end = bbase[b + 1];

    for (int i = t; i < BKT_SIZE * 9; i += 512) acc[i] = 0.0f;
    if (t < 70) { sWr[t] = Wrel[t]; sWo[t] = Wroot[t]; }
    if (t < 10) sb[t] = brel[t];
    __syncthreads();

    int sub = t & 1;             // which float4 half of the row
    int e = start + (t >> 1);
    const int estep = 256;
    while (e + estep < end) {
        unsigned int p0 = pairs[e], p1 = pairs[e + estep];
        float4 v0 = *(const float4*)(h2 + (size_t)(p0 >> BKT_BITS) * 8 + sub * 4);
        float4 v1 = *(const float4*)(h2 + (size_t)(p1 >> BKT_BITS) * 8 + sub * 4);
        int l0 = (int)(p0 & (BKT_SIZE - 1)) * 9 + sub * 4;
        int l1 = (int)(p1 & (BKT_SIZE - 1)) * 9 + sub * 4;
        atomicAdd(&acc[l0 + 0], v0.x); atomicAdd(&acc[l0 + 1], v0.y);
        atomicAdd(&acc[l0 + 2], v0.z); atomicAdd(&acc[l0 + 3], v0.w);
        atomicAdd(&acc[l1 + 0], v1.x); atomicAdd(&acc[l1 + 1], v1.y);
        atomicAdd(&acc[l1 + 2], v1.z); atomicAdd(&acc[l1 + 3], v1.w);
        e += 2 * estep;
    }
    while (e < end) {
        unsigned int p = pairs[e];
        float4 v = *(const float4*)(h2 + (size_t)(p >> BKT_BITS) * 8 + sub * 4);
        int l = (int)(p & (BKT_SIZE - 1)) * 9 + sub * 4;
        atomicAdd(&acc[l + 0], v.x); atomicAdd(&acc[l + 1], v.y);
        atomicAdd(&acc[l + 2], v.z); atomicAdd(&acc[l + 3], v.w);
        e += estep;
    }
    __syncthreads();

    for (int i = t; i < BKT_SIZE; i += 512) {
        int node = base + i;
        if (node >= N_NODES) continue;
        float a[7];
#pragma unroll
        for (int k = 0; k < 7; ++k) a[k] = acc[i * 9 + k];
        const float4* hp = (const float4*)(h2 + (size_t)node * 8);
        float4 x0 = hp[0], x1 = hp[1];
        float xin[7] = {x0.x, x0.y, x0.z, x0.w, x1.x, x1.y, x1.z};
        float o_[16];
#pragma unroll
        for (int o = 0; o < 10; ++o) {
            float v = sb[o];
#pragma unroll
            for (int k = 0; k < 7; ++k)
                v += a[k] * sWr[k * 10 + o] + xin[k] * sWo[k * 10 + o];
            o_[o] = fmaxf(v, 0.0f);
        }
#pragma unroll
        for (int o = 10; o < 16; ++o) o_[o] = 0.0f;
        float4* op = (float4*)(h3 + (size_t)node * 16);
        op[0] = make_float4(o_[0],  o_[1],  o_[2],  o_[3]);
        op[1] = make_float4(o_[4],  o_[5],  o_[6],  o_[7]);
        op[2] = make_float4(o_[8],  o_[9],  o_[10], o_[11]);
        op[3] = make_float4(o_[12], o_[13], o_[14], o_[15]);
    }
}

// ---------------------------------------------------------------------------
// Layer 4 (din=10, stride 16) + full MLP. 4 lanes per edge; sub==3 covers
// cols 12..15 which are all zero -> skipped. acc stride 13 (cols 0..11).
// ---------------------------------------------------------------------------
__global__ __launch_bounds__(512) void layer4_kernel(
    const int* __restrict__ bbase, const unsigned int* __restrict__ pairs,
    const float* __restrict__ h3,
    const float* __restrict__ g4Wrel, const float* __restrict__ g4brel,
    const float* __restrict__ g4Wroot,
    const float* __restrict__ fc1W, const float* __restrict__ fc1b,
    const float* __restrict__ fc2W, const float* __restrict__ fc2b,
    const float* __restrict__ fc3W, const float* __restrict__ fc3b,
    float* __restrict__ out)
{
    __shared__ float acc[BKT_SIZE * 13];   // 52 KB
    __shared__ float s[1680];              // MLP + g4 weights (6.7 KB)
    float* sWrel  = s;            // 160
    float* sbrel  = s + 160;      // 16
    float* sWroot = s + 176;      // 160
    float* sfc1W  = s + 336;      // 512
    float* sfc1b  = s + 848;      // 32
    float* sfc2W  = s + 880;      // 512
    float* sfc2b  = s + 1392;     // 16
    float* sfc3W  = s + 1408;     // 256
    float* sfc3b  = s + 1664;     // 16

    int b = blockIdx.x, t = threadIdx.x;
    int base = b << BKT_BITS;
    int start = bbase[b], end = bbase[b + 1];

    for (int i = t; i < BKT_SIZE * 13; i += 512) acc[i] = 0.0f;
    for (int i = t; i < 160; i += 512) { sWrel[i] = g4Wrel[i]; sWroot[i] = g4Wroot[i]; }
    for (int i = t; i < 512; i += 512) { sfc1W[i] = fc1W[i]; sfc2W[i] = fc2W[i]; }
    if (t < 256) sfc3W[t] = fc3W[t];
    if (t < 32)  sfc1b[t] = fc1b[t];
    if (t < 16)  { sbrel[t] = g4brel[t]; sfc2b[t] = fc2b[t]; sfc3b[t] = fc3b[t]; }
    __syncthreads();

    int sub = t & 3;
    int e = start + (t >> 2);
    const int estep = 128;
    if (sub < 3) {
        while (e + estep < end) {
            unsigned int p0 = pairs[e], p1 = pairs[e + estep];
            float4 v0 = *(const float4*)(h3 + (size_t)(p0 >> BKT_BITS) * 16 + sub * 4);
            float4 v1 = *(const float4*)(h3 + (size_t)(p1 >> BKT_BITS) * 16 + sub * 4);
            int l0 = (int)(p0 & (BKT_SIZE - 1)) * 13 + sub * 4;
            int l1 = (int)(p1 & (BKT_SIZE - 1)) * 13 + sub * 4;
            atomicAdd(&acc[l0 + 0], v0.x); atomicAdd(&acc[l0 + 1], v0.y);
            atomicAdd(&acc[l0 + 2], v0.z); atomicAdd(&acc[l0 + 3], v0.w);
            atomicAdd(&acc[l1 + 0], v1.x); atomicAdd(&acc[l1 + 1], v1.y);
            atomicAdd(&acc[l1 + 2], v1.z); atomicAdd(&acc[l1 + 3], v1.w);
            e += 2 * estep;
        }
        while (e < end) {
            unsigned int p = pairs[e];
            float4 v = *(const float4*)(h3 + (size_t)(p >> BKT_BITS) * 16 + sub * 4);
            int l = (int)(p & (BKT_SIZE - 1)) * 13 + sub * 4;
            atomicAdd(&acc[l + 0], v.x); atomicAdd(&acc[l + 1], v.y);
            atomicAdd(&acc[l + 2], v.z); atomicAdd(&acc[l + 3], v.w);
            e += estep;
        }
    }
    __syncthreads();

    for (int i = t; i < BKT_SIZE; i += 512) {
        int node = base + i;
        if (node >= N_NODES) continue;
        float a[10], xin[10];
#pragma unroll
        for (int k = 0; k < 10; ++k) a[k] = acc[i * 13 + k];
        const float4* hp = (const float4*)(h3 + (size_t)node * 16);
        float4 x0 = hp[0], x1 = hp[1], x2 = hp[2];
        xin[0] = x0.x; xin[1] = x0.y; xin[2] = x0.z; xin[3] = x0.w;
        xin[4] = x1.x; xin[5] = x1.y; xin[6] = x1.z; xin[7] = x1.w;
        xin[8] = x2.x; xin[9] = x2.y;

        float h4[16];
#pragma unroll
        for (int o = 0; o < 16; ++o) {
            float v = sbrel[o];
#pragma unroll
            for (int k = 0; k < 10; ++k)
                v += a[k] * sWrel[k * 16 + o] + xin[k] * sWroot[k * 16 + o];
            h4[o] = fmaxf(v, 0.0f);
        }
        float m1[32];
#pragma unroll
        for (int o = 0; o < 32; ++o) {
            float v = sfc1b[o];
#pragma unroll
            for (int k = 0; k < 16; ++k) v += h4[k] * sfc1W[k * 32 + o];
            m1[o] = fmaxf(v, 0.0f);
        }
        float m2[16];
#pragma unroll
        for (int o = 0; o < 16; ++o) {
            float v = sfc2b[o];
#pragma unroll
            for (int k = 0; k < 32; ++k) v += m1[k] * sfc2W[k * 16 + o];
            m2[o] = fmaxf(v, 0.0f);
        }
        float r[16];
#pragma unroll
        for (int o = 0; o < 16; ++o) {
            float v = sfc3b[o];
#pragma unroll
            for (int k = 0; k < 16; ++k) v += m2[k] * sfc3W[k * 16 + o];
            r[o] = v;
        }
        float4* op = (float4*)(out + (size_t)node * 16);
#pragma unroll
        for (int q = 0; q < 4; ++q)
            op[q] = make_float4(r[q * 4 + 0], r[q * 4 + 1], r[q * 4 + 2], r[q * 4 + 3]);
    }
}

// ---------------------------------------------------------------------------
extern "C" void kernel_launch(void* const* d_in, const int* in_sizes, int n_in,
                              void* d_out, int out_size, void* d_ws, size_t ws_size,
                              hipStream_t stream) {
    const float* x        = (const float*)d_in[0];
    const int*   ei       = (const int*)d_in[1];
    const float* g1_Wrel  = (const float*)d_in[2];
    const float* g1_brel  = (const float*)d_in[3];
    const float* g1_Wroot = (const float*)d_in[4];
    const float* g2_Wrel  = (const float*)d_in[5];
    const float* g2_brel  = (const float*)d_in[6];
    const float* g2_Wroot = (const float*)d_in[7];
    const float* g3_Wrel  = (const float*)d_in[8];
    const float* g3_brel  = (const float*)d_in[9];
    const float* g3_Wroot = (const float*)d_in[10];
    const float* g4_Wrel  = (const float*)d_in[11];
    const float* g4_brel  = (const float*)d_in[12];
    const float* g4_Wroot = (const float*)d_in[13];
    const float* fc1_W    = (const float*)d_in[14];
    const float* fc1_b    = (const float*)d_in[15];
    const float* fc2_W    = (const float*)d_in[16];
    const float* fc2_b    = (const float*)d_in[17];
    const float* fc3_W    = (const float*)d_in[18];
    const float* fc3_b    = (const float*)d_in[19];
    float* out = (float*)d_out;

    const int* srcp = ei;
    const int* dstp = ei + N_EDGES;

    // ---- workspace layout (256B aligned), ~120 MB total ----
    char* p = (char*)d_ws;
    auto alloc = [&](size_t bytes) {
        char* r = p;
        p += (bytes + 255) & ~(size_t)255;
        return r;
    };
    int*   bhist = (int*)  alloc((size_t)NBUCKET * 4);
    int*   bbase = (int*)  alloc((size_t)(NBUCKET + 1) * 4);
    int*   bcur  = (int*)  alloc((size_t)NBUCKET * 4);
    float* h1p   = (float*)alloc((size_t)N_NODES * 4 * 4);      //  8 MB
    float* h2p   = (float*)alloc((size_t)N_NODES * 8 * 4);      // 16 MB
    float* h3p   = (float*)alloc((size_t)N_NODES * 16 * 4);     // 32 MB
    unsigned int* pairs = (unsigned int*)alloc((size_t)N_EDGES * 4); // 64 MB

    // ---- bucket the edge list (dst-bucket granularity only) ----
    hipMemsetAsync(bhist, 0, (size_t)NBUCKET * 4, stream);
    bucket_hist_kernel<<<BIN_NBLK, 256, 0, stream>>>(dstp, bhist);
    bucket_scan_kernel<<<1, 512, 0, stream>>>(bhist, bbase, bcur);
    bin_kernel<<<BIN_NBLK, 256, 0, stream>>>(srcp, dstp, bcur, pairs);

    // ---- fused per-bucket aggregate+transform layers ----
    layer1_kernel<<<NBUCKET, 512, 0, stream>>>(bbase, pairs, x,
        g1_Wrel, g1_brel, g1_Wroot, h1p);
    layer2_kernel<<<NBUCKET, 512, 0, stream>>>(bbase, pairs, h1p,
        g2_Wrel, g2_brel, g2_Wroot, h2p);
    layer3_kernel<<<NBUCKET, 512, 0, stream>>>(bbase, pairs, h2p,
        g3_Wrel, g3_brel, g3_Wroot, h3p);
    layer4_kernel<<<NBUCKET, 512, 0, stream>>>(bbase, pairs, h3p,
        g4_Wrel, g4_brel, g4_Wroot,
        fc1_W, fc1_b, fc2_W, fc2_b, fc3_W, fc3_b, out);
}

// Round 7
// 1198.988 us; speedup vs baseline: 2.1002x; 2.1002x over previous
//
#include <hip/hip_runtime.h>
#include <hip/hip_fp16.h>

#define N_NODES 500000
#define N_EDGES 16000000

// bucketing: 1024 dst-nodes per bucket
#define BKT_BITS 10
#define BKT_SIZE (1 << BKT_BITS)
#define NBUCKET ((N_NODES + BKT_SIZE - 1) / BKT_SIZE)       // 489
#define BIN_EPT 128
#define BIN_CHUNK (256 * BIN_EPT)                            // 32768 edges
#define BIN_NBLK ((N_EDGES + BIN_CHUNK - 1) / BIN_CHUNK)     // 489
#define BIN_VQ (BIN_EPT / 4)                                 // 32 int4/thread
#define NV4 (N_EDGES / 4)                                    // 4M int4

// ---------------------------------------------------------------------------
// Bucket histogram (489 bins): per-block LDS aggregation, int4 edge reads.
// ---------------------------------------------------------------------------
__global__ __launch_bounds__(256) void bucket_hist_kernel(
    const int* __restrict__ dst, int* __restrict__ bhist)
{
    __shared__ int lh[NBUCKET];
    const int4* dst4 = (const int4*)dst;
    int t = threadIdx.x;
    long v0 = (long)blockIdx.x * (BIN_CHUNK / 4);
    for (int b = t; b < NBUCKET; b += 256) lh[b] = 0;
    __syncthreads();
#pragma unroll
    for (int q = 0; q < BIN_VQ; ++q) {
        long v = v0 + q * 256 + t;
        if (v < NV4) {
            int4 d = dst4[v];
            atomicAdd(&lh[d.x >> BKT_BITS], 1);
            atomicAdd(&lh[d.y >> BKT_BITS], 1);
            atomicAdd(&lh[d.z >> BKT_BITS], 1);
            atomicAdd(&lh[d.w >> BKT_BITS], 1);
        }
    }
    __syncthreads();
    for (int b = t; b < NBUCKET; b += 256) {
        int c = lh[b];
        if (c) atomicAdd(&bhist[b], c);
    }
}

// single-block exclusive scan of 489 bucket totals -> bbase[0..NBUCKET], bcur
__global__ __launch_bounds__(512) void bucket_scan_kernel(
    const int* __restrict__ bhist, int* __restrict__ bbase, int* __restrict__ bcur)
{
    __shared__ int sdata[512];
    int t = threadIdx.x;
    int v = (t < NBUCKET) ? bhist[t] : 0;
    sdata[t] = v;
    __syncthreads();
    for (int o = 1; o < 512; o <<= 1) {
        int tmp = (t >= o) ? sdata[t - o] : 0;
        __syncthreads();
        sdata[t] += tmp;
        __syncthreads();
    }
    if (t < NBUCKET) {
        int excl = sdata[t] - v;
        bbase[t] = excl;
        bcur[t] = excl;
        if (t == NBUCKET - 1) bbase[NBUCKET] = sdata[t];
    }
}

// ---------------------------------------------------------------------------
// Bin edges into buckets. pairs[pos] = (src<<10)|(dst&1023)
// ---------------------------------------------------------------------------
__global__ __launch_bounds__(256) void bin_kernel(
    const int* __restrict__ src, const int* __restrict__ dst,
    int* __restrict__ bcur, unsigned int* __restrict__ pairs)
{
    __shared__ int lh[NBUCKET];
    __shared__ int lbase[NBUCKET];
    const int4* dst4 = (const int4*)dst;
    const int4* src4 = (const int4*)src;
    int t = threadIdx.x;
    long v0 = (long)blockIdx.x * (BIN_CHUNK / 4);

    for (int b = t; b < NBUCKET; b += 256) lh[b] = 0;
    __syncthreads();

#pragma unroll
    for (int q = 0; q < BIN_VQ; ++q) {
        long v = v0 + q * 256 + t;
        if (v < NV4) {
            int4 d = dst4[v];
            atomicAdd(&lh[d.x >> BKT_BITS], 1);
            atomicAdd(&lh[d.y >> BKT_BITS], 1);
            atomicAdd(&lh[d.z >> BKT_BITS], 1);
            atomicAdd(&lh[d.w >> BKT_BITS], 1);
        }
    }
    __syncthreads();

    for (int b = t; b < NBUCKET; b += 256) {
        int c = lh[b];
        lbase[b] = c ? atomicAdd(&bcur[b], c) : 0;
        lh[b] = 0;   // reuse as running counter
    }
    __syncthreads();

#pragma unroll
    for (int q = 0; q < BIN_VQ; ++q) {
        long v = v0 + q * 256 + t;
        if (v < NV4) {
            int4 d = dst4[v];
            int4 s = src4[v];
            {
                int b = d.x >> BKT_BITS;
                int r = atomicAdd(&lh[b], 1);
                pairs[lbase[b] + r] = ((unsigned int)s.x << BKT_BITS) | (unsigned int)(d.x & (BKT_SIZE - 1));
            }
            {
                int b = d.y >> BKT_BITS;
                int r = atomicAdd(&lh[b], 1);
                pairs[lbase[b] + r] = ((unsigned int)s.y << BKT_BITS) | (unsigned int)(d.y & (BKT_SIZE - 1));
            }
            {
                int b = d.z >> BKT_BITS;
                int r = atomicAdd(&lh[b], 1);
                pairs[lbase[b] + r] = ((unsigned int)s.z << BKT_BITS) | (unsigned int)(d.z & (BKT_SIZE - 1));
            }
            {
                int b = d.w >> BKT_BITS;
                int r = atomicAdd(&lh[b], 1);
                pairs[lbase[b] + r] = ((unsigned int)s.w << BKT_BITS) | (unsigned int)(d.w & (BKT_SIZE - 1));
            }
        }
    }
}

// ---------------------------------------------------------------------------
// One block per bucket: LDS histogram + scan -> off[] + cursors; place edges
// into contiguous window. FUSED: layer-1 aggregation agg1[i] = sum x[src].
// ---------------------------------------------------------------------------
__global__ __launch_bounds__(256) void bucket_sort_kernel(
    const int* __restrict__ bbase, const unsigned int* __restrict__ pairs,
    const float* __restrict__ xfeat,
    int* __restrict__ off, int* __restrict__ sorted_src,
    float* __restrict__ agg1)
{
    __shared__ int lh[BKT_SIZE];     // histogram -> cursors
    __shared__ float laccum[BKT_SIZE];
    __shared__ int sdata[256];
    int b = blockIdx.x;
    int t = threadIdx.x;
    int base_node = b << BKT_BITS;
    int start = bbase[b];
    int end = bbase[b + 1];

    for (int i = t; i < BKT_SIZE; i += 256) { lh[i] = 0; laccum[i] = 0.0f; }
    __syncthreads();

    for (int e = start + t; e < end; e += 256)
        atomicAdd(&lh[pairs[e] & (BKT_SIZE - 1)], 1);
    __syncthreads();

    int i0 = t * 4;
    int c0 = lh[i0], c1 = lh[i0 + 1], c2 = lh[i0 + 2], c3 = lh[i0 + 3];
    int s = c0 + c1 + c2 + c3;
    sdata[t] = s;
    __syncthreads();
    for (int o = 1; o < 256; o <<= 1) {
        int tmp = (t >= o) ? sdata[t - o] : 0;
        __syncthreads();
        sdata[t] += tmp;
        __syncthreads();
    }
    int run = start + sdata[t] - s;
    int vals[4] = {c0, c1, c2, c3};
#pragma unroll
    for (int q = 0; q < 4; ++q) {
        int node = base_node + i0 + q;
        if (node < N_NODES) {
            off[node] = run;
            if (node == N_NODES - 1) off[N_NODES] = run + vals[q];
        }
        lh[i0 + q] = run;
        run += vals[q];
    }
    __syncthreads();

    for (int e = start + t; e < end; e += 256) {
        unsigned int p = pairs[e];
        int low = (int)(p & (BKT_SIZE - 1));
        int sidx = (int)(p >> BKT_BITS);
        int pos = atomicAdd(&lh[low], 1);
        sorted_src[pos] = sidx;
        atomicAdd(&laccum[low], xfeat[sidx]);
    }
    __syncthreads();

    for (int i = t; i < BKT_SIZE; i += 256) {
        int node = base_node + i;
        if (node < N_NODES) agg1[node] = laccum[i];
    }
}

// ---------------------------------------------------------------------------
// Gather (fp16 h): L half2 units per row, L lanes per node. Broadcast ss
// loads + 4-edge unroll -> 4+ independent loads in flight per lane.
// agg row stride = 2L floats.
// ---------------------------------------------------------------------------
template<int L>
__global__ __launch_bounds__(256) void gather_h_kernel(
    const int* __restrict__ off, const int* __restrict__ ss,
    const __half2* __restrict__ h, float* __restrict__ agg)
{
    const int npb = 256 / L;
    int node = blockIdx.x * npb + threadIdx.x / L;
    int j = threadIdx.x % L;
    if (node >= N_NODES) return;
    int start = off[node], end = off[node + 1];

    float ax = 0, ay = 0, bx = 0, by = 0, cx = 0, cy = 0, dx = 0, dy = 0;
    int e = start;
    for (; e + 4 <= end; e += 4) {
        int s0 = ss[e], s1 = ss[e + 1], s2 = ss[e + 2], s3 = ss[e + 3];
        __half2 u0 = h[(size_t)s0 * L + j];
        __half2 u1 = h[(size_t)s1 * L + j];
        __half2 u2 = h[(size_t)s2 * L + j];
        __half2 u3 = h[(size_t)s3 * L + j];
        float2 f0 = __half22float2(u0), f1 = __half22float2(u1);
        float2 f2 = __half22float2(u2), f3 = __half22float2(u3);
        ax += f0.x; ay += f0.y;
        bx += f1.x; by += f1.y;
        cx += f2.x; cy += f2.y;
        dx += f3.x; dy += f3.y;
    }
    for (; e < end; ++e) {
        int s0 = ss[e];
        float2 f = __half22float2(h[(size_t)s0 * L + j]);
        ax += f.x; ay += f.y;
    }
    float rx = (ax + bx) + (cx + dx);
    float ry = (ay + by) + (cy + dy);
    ((float2*)agg)[(size_t)node * L + j] = make_float2(rx, ry);
}

// ---------------------------------------------------------------------------
// transform1: h1 = relu(agg1*Wrel + brel + x*Wroot)   [1 -> 4], h1 fp16
// ---------------------------------------------------------------------------
__global__ __launch_bounds__(256) void transform1_kernel(
    const float* __restrict__ agg1, const float* __restrict__ x,
    const float* __restrict__ Wrel, const float* __restrict__ brel,
    const float* __restrict__ Wroot,
    __half2* __restrict__ h1)
{
    __shared__ float w[12];
    if (threadIdx.x < 4) {
        w[threadIdx.x] = Wrel[threadIdx.x];
        w[4 + threadIdx.x] = brel[threadIdx.x];
        w[8 + threadIdx.x] = Wroot[threadIdx.x];
    }
    __syncthreads();
    int i = blockIdx.x * blockDim.x + threadIdx.x;
    if (i >= N_NODES) return;
    float a = agg1[i], xv = x[i];
    float r0 = fmaxf(a * w[0] + w[4] + xv * w[8],  0.0f);
    float r1 = fmaxf(a * w[1] + w[5] + xv * w[9],  0.0f);
    float r2 = fmaxf(a * w[2] + w[6] + xv * w[10], 0.0f);
    float r3 = fmaxf(a * w[3] + w[7] + xv * w[11], 0.0f);
    h1[(size_t)i * 2 + 0] = __floats2half2_rn(r0, r1);
    h1[(size_t)i * 2 + 1] = __floats2half2_rn(r2, r3);
}

// ---------------------------------------------------------------------------
// transform2: h2 = relu(agg@Wrel + brel + h1@Wroot)   [4 -> 7], h2 fp16 pad 8
// ---------------------------------------------------------------------------
__global__ __launch_bounds__(256) void transform2_kernel(
    const float* __restrict__ agg, const __half2* __restrict__ h1,
    const float* __restrict__ Wrel, const float* __restrict__ brel,
    const float* __restrict__ Wroot,
    __half2* __restrict__ h2)
{
    __shared__ float sWr[28], sWo[28], sb[7];
    int t = threadIdx.x;
    if (t < 28) { sWr[t] = Wrel[t]; sWo[t] = Wroot[t]; }
    if (t < 7) sb[t] = brel[t];
    __syncthreads();
    int i = blockIdx.x * blockDim.x + threadIdx.x;
    if (i >= N_NODES) return;
    float4 a = ((const float4*)agg)[i];
    float2 x01 = __half22float2(h1[(size_t)i * 2]);
    float2 x23 = __half22float2(h1[(size_t)i * 2 + 1]);
    float av[4] = {a.x, a.y, a.z, a.w};
    float xv[4] = {x01.x, x01.y, x23.x, x23.y};
    float o_[8];
#pragma unroll
    for (int o = 0; o < 7; ++o) {
        float v = sb[o];
#pragma unroll
        for (int k = 0; k < 4; ++k)
            v += av[k] * sWr[k * 7 + o] + xv[k] * sWo[k * 7 + o];
        o_[o] = fmaxf(v, 0.0f);
    }
    o_[7] = 0.0f;
#pragma unroll
    for (int q = 0; q < 4; ++q)
        h2[(size_t)i * 4 + q] = __floats2half2_rn(o_[2 * q], o_[2 * q + 1]);
}

// ---------------------------------------------------------------------------
// transform3: h3 = relu(agg@Wrel + brel + h2@Wroot)   [7 -> 10], h3 fp16 pad 16
// ---------------------------------------------------------------------------
__global__ __launch_bounds__(256) void transform3_kernel(
    const float* __restrict__ agg, const __half2* __restrict__ h2,
    const float* __restrict__ Wrel, const float* __restrict__ brel,
    const float* __restrict__ Wroot,
    __half2* __restrict__ h3)
{
    __shared__ float sWr[70], sWo[70], sb[10];
    int t = threadIdx.x;
    if (t < 70) { sWr[t] = Wrel[t]; sWo[t] = Wroot[t]; }
    if (t < 10) sb[t] = brel[t];
    __syncthreads();
    int i = blockIdx.x * blockDim.x + threadIdx.x;
    if (i >= N_NODES) return;
    const float4* ap = (const float4*)(agg + (size_t)i * 8);
    float4 a0 = ap[0], a1 = ap[1];
    float av[7] = {a0.x, a0.y, a0.z, a0.w, a1.x, a1.y, a1.z};
    float xv[8];
#pragma unroll
    for (int q = 0; q < 4; ++q) {
        float2 f = __half22float2(h2[(size_t)i * 4 + q]);
        xv[2 * q] = f.x; xv[2 * q + 1] = f.y;
    }
    float o_[16];
#pragma unroll
    for (int o = 0; o < 10; ++o) {
        float v = sb[o];
#pragma unroll
        for (int k = 0; k < 7; ++k)
            v += av[k] * sWr[k * 10 + o] + xv[k] * sWo[k * 10 + o];
        o_[o] = fmaxf(v, 0.0f);
    }
#pragma unroll
    for (int o = 10; o < 16; ++o) o_[o] = 0.0f;
#pragma unroll
    for (int q = 0; q < 8; ++q)
        h3[(size_t)i * 8 + q] = __floats2half2_rn(o_[2 * q], o_[2 * q + 1]);
}

// ---------------------------------------------------------------------------
// layer4 transform + 3-layer MLP. agg stride 16 fp32 (cols 0..9), h3 fp16.
// ---------------------------------------------------------------------------
__global__ __launch_bounds__(256) void layer4_mlp_kernel(
    const float* __restrict__ agg, const __half2* __restrict__ h3,
    const float* __restrict__ g4Wrel, const float* __restrict__ g4brel,
    const float* __restrict__ g4Wroot,
    const float* __restrict__ fc1W, const float* __restrict__ fc1b,
    const float* __restrict__ fc2W, const float* __restrict__ fc2b,
    const float* __restrict__ fc3W, const float* __restrict__ fc3b,
    float* __restrict__ out)
{
    __shared__ float s[1680];
    float* sWrel  = s;            // 160
    float* sbrel  = s + 160;      // 16
    float* sWroot = s + 176;      // 160
    float* sfc1W  = s + 336;      // 512
    float* sfc1b  = s + 848;      // 32
    float* sfc2W  = s + 880;      // 512
    float* sfc2b  = s + 1392;     // 16
    float* sfc3W  = s + 1408;     // 256
    float* sfc3b  = s + 1664;     // 16
    int t = threadIdx.x;
    for (int i = t; i < 160; i += 256) { sWrel[i] = g4Wrel[i]; sWroot[i] = g4Wroot[i]; }
    for (int i = t; i < 512; i += 256) { sfc1W[i] = fc1W[i]; sfc2W[i] = fc2W[i]; }
    if (t < 256) sfc3W[t] = fc3W[t];
    if (t < 32)  sfc1b[t] = fc1b[t];
    if (t < 16)  { sbrel[t] = g4brel[t]; sfc2b[t] = fc2b[t]; sfc3b[t] = fc3b[t]; }
    __syncthreads();

    int i = blockIdx.x * blockDim.x + threadIdx.x;
    if (i >= N_NODES) return;

    const float4* ap = (const float4*)(agg + (size_t)i * 16);
    float4 a0 = ap[0], a1 = ap[1], a2 = ap[2];
    float a[10] = {a0.x, a0.y, a0.z, a0.w, a1.x, a1.y, a1.z, a1.w, a2.x, a2.y};
    float xin[10];
#pragma unroll
    for (int q = 0; q < 5; ++q) {
        float2 f = __half22float2(h3[(size_t)i * 8 + q]);
        xin[2 * q] = f.x; xin[2 * q + 1] = f.y;
    }

    float h4[16];
#pragma unroll
    for (int o = 0; o < 16; ++o) {
        float v = sbrel[o];
#pragma unroll
        for (int k = 0; k < 10; ++k)
            v += a[k] * sWrel[k * 16 + o] + xin[k] * sWroot[k * 16 + o];
        h4[o] = fmaxf(v, 0.0f);
    }
    float m1[32];
#pragma unroll
    for (int o = 0; o < 32; ++o) {
        float v = sfc1b[o];
#pragma unroll
        for (int k = 0; k < 16; ++k) v += h4[k] * sfc1W[k * 32 + o];
        m1[o] = fmaxf(v, 0.0f);
    }
    float m2[16];
#pragma unroll
    for (int o = 0; o < 16; ++o) {
        float v = sfc2b[o];
#pragma unroll
        for (int k = 0; k < 32; ++k) v += m1[k] * sfc2W[k * 16 + o];
        m2[o] = fmaxf(v, 0.0f);
    }
    float r[16];
#pragma unroll
    for (int o = 0; o < 16; ++o) {
        float v = sfc3b[o];
#pragma unroll
        for (int k = 0; k < 16; ++k) v += m2[k] * sfc3W[k * 16 + o];
        r[o] = v;
    }
    float4* op = (float4*)(out + (size_t)i * 16);
#pragma unroll
    for (int q = 0; q < 4; ++q)
        op[q] = make_float4(r[q * 4 + 0], r[q * 4 + 1], r[q * 4 + 2], r[q * 4 + 3]);
}

// ---------------------------------------------------------------------------
extern "C" void kernel_launch(void* const* d_in, const int* in_sizes, int n_in,
                              void* d_out, int out_size, void* d_ws, size_t ws_size,
                              hipStream_t stream) {
    const float* x        = (const float*)d_in[0];
    const int*   ei       = (const int*)d_in[1];
    const float* g1_Wrel  = (const float*)d_in[2];
    const float* g1_brel  = (const float*)d_in[3];
    const float* g1_Wroot = (const float*)d_in[4];
    const float* g2_Wrel  = (const float*)d_in[5];
    const float* g2_brel  = (const float*)d_in[6];
    const float* g2_Wroot = (const float*)d_in[7];
    const float* g3_Wrel  = (const float*)d_in[8];
    const float* g3_brel  = (const float*)d_in[9];
    const float* g3_Wroot = (const float*)d_in[10];
    const float* g4_Wrel  = (const float*)d_in[11];
    const float* g4_brel  = (const float*)d_in[12];
    const float* g4_Wroot = (const float*)d_in[13];
    const float* fc1_W    = (const float*)d_in[14];
    const float* fc1_b    = (const float*)d_in[15];
    const float* fc2_W    = (const float*)d_in[16];
    const float* fc2_b    = (const float*)d_in[17];
    const float* fc3_W    = (const float*)d_in[18];
    const float* fc3_b    = (const float*)d_in[19];
    float* out = (float*)d_out;

    const int* srcp = ei;
    const int* dstp = ei + N_EDGES;

    // ---- workspace layout (256B aligned), ~136 MB ----
    char* p = (char*)d_ws;
    auto alloc = [&](size_t bytes) {
        char* r = p;
        p += (bytes + 255) & ~(size_t)255;
        return r;
    };
    // alias region: pairs (64MB) spans h1+h2+h3+agg+pad; all consumers of
    // pairs (bucket_sort) finish before any of these are written.
    __half2* h1  = (__half2*)alloc((size_t)N_NODES * 4 * 2);   //  4 MB
    __half2* h2  = (__half2*)alloc((size_t)N_NODES * 8 * 2);   //  8 MB
    __half2* h3  = (__half2*)alloc((size_t)N_NODES * 16 * 2);  // 16 MB
    float*   agg = (float*)  alloc((size_t)N_NODES * 16 * 4);  // 32 MB
    alloc((size_t)8 * 1024 * 1024);                            //  8 MB pad
    unsigned int* pairs = (unsigned int*)h1;                   // 64 MB alias
    int*   sorted_src = (int*)alloc((size_t)N_EDGES * 4);      // 64 MB
    int*   off   = (int*)alloc((size_t)(N_NODES + 1) * 4);     //  2 MB
    float* agg1  = (float*)alloc((size_t)N_NODES * 4);         //  2 MB
    int*   bhist = (int*)alloc((size_t)NBUCKET * 4);
    int*   bbase = (int*)alloc((size_t)(NBUCKET + 1) * 4);
    int*   bcur  = (int*)alloc((size_t)NBUCKET * 4);

    const int TB = 256;
    const int node_blocks = (N_NODES + TB - 1) / TB;

    // ---- build CSR (binned counting sort by dst) + fused layer-1 agg ----
    hipMemsetAsync(bhist, 0, (size_t)NBUCKET * 4, stream);
    bucket_hist_kernel<<<BIN_NBLK, 256, 0, stream>>>(dstp, bhist);
    bucket_scan_kernel<<<1, 512, 0, stream>>>(bhist, bbase, bcur);
    bin_kernel<<<BIN_NBLK, 256, 0, stream>>>(srcp, dstp, bcur, pairs);
    bucket_sort_kernel<<<NBUCKET, 256, 0, stream>>>(bbase, pairs, x, off, sorted_src, agg1);

    // ---- layer 1: transform only (agg fused above); h1 fp16 ----
    transform1_kernel<<<node_blocks, TB, 0, stream>>>(
        agg1, x, g1_Wrel, g1_brel, g1_Wroot, h1);

    // ---- layer 2: gather h1 (L=2) -> agg stride 4; transform -> h2 fp16 ----
    gather_h_kernel<2><<<(N_NODES + 127) / 128, TB, 0, stream>>>(off, sorted_src, h1, agg);
    transform2_kernel<<<node_blocks, TB, 0, stream>>>(
        agg, h1, g2_Wrel, g2_brel, g2_Wroot, h2);

    // ---- layer 3: gather h2 (L=4) -> agg stride 8; transform -> h3 fp16 ----
    gather_h_kernel<4><<<(N_NODES + 63) / 64, TB, 0, stream>>>(off, sorted_src, h2, agg);
    transform3_kernel<<<node_blocks, TB, 0, stream>>>(
        agg, h2, g3_Wrel, g3_brel, g3_Wroot, h3);

    // ---- layer 4: gather h3 (L=8) -> agg stride 16; fused transform+MLP ----
    gather_h_kernel<8><<<(N_NODES + 31) / 32, TB, 0, stream>>>(off, sorted_src, h3, agg);
    layer4_mlp_kernel<<<node_blocks, TB, 0, stream>>>(
        agg, h3, g4_Wrel, g4_brel, g4_Wroot,
        fc1_W, fc1_b, fc2_W, fc2_b, fc3_W, fc3_b, out);
}